// Round 3
// baseline (163.995 us; speedup 1.0000x reference)
//
#include <hip/hip_runtime.h>

typedef __attribute__((ext_vector_type(8))) short short8;
typedef __attribute__((ext_vector_type(4))) float floatx4;

#define D 128
#define NWAVES 4

// bf16 MFMA B-fragment buffer for W1,W2: 2*128*128 bf16 = 64 KB.
// Module-scope device global (NOT workspace: ws_size is exactly nNodes*D*2).
__device__ unsigned short g_wq[2 * D * D];

__device__ __forceinline__ unsigned short f2bf(float f) {
  unsigned u = __float_as_uint(f);
  u += 0x7FFFu + ((u >> 16) & 1u);   // RNE
  return (unsigned short)(u >> 16);
}

// One-shot W prep: convert fp32 W1,W2 -> bf16 laid out in exact MFMA
// B-fragment order. Per layer: 32 fragments (kk*8+n0) x 64 lanes x 8 elems
// = 16384 elements. Total 32768 threads (128 blocks x 256).
//   g_wq[layer*16384 + fragid*512 + lane*8 + e]
//     = W[(kk*32 + (lane>>4)*8 + e)*D + n0*16 + (lane&15)]
// so mlp waves load B-frags as one coalesced 16B/lane global read
// (64 KB total -> L1/L2-resident across all waves).
__global__ __launch_bounds__(256) void prep_w(const float* __restrict__ W1,
                                              const float* __restrict__ W2) {
  const int t = blockIdx.x * 256 + threadIdx.x;   // 32768 total
  const int layer = t >> 14;
  const int r = t & 16383;
  const int fragid = r >> 9;          // kk*8 + n0, [0,32)
  const int lane = (r >> 3) & 63;
  const int e = r & 7;
  const int kk = fragid >> 3, n0 = fragid & 7;
  const int k = kk * 32 + (lane >> 4) * 8 + e;    // [0,128)
  const int n = n0 * 16 + (lane & 15);            // [0,128)
  const float* W = layer ? W2 : W1;
  g_wq[t] = f2bf(W[k * D + n]);
}

__device__ __forceinline__ short8 cvt_a(const floatx4& f0, const floatx4& f1) {
  short8 a;
  a[0] = (short)f2bf(f0[0]); a[1] = (short)f2bf(f0[1]);
  a[2] = (short)f2bf(f0[2]); a[3] = (short)f2bf(f0[3]);
  a[4] = (short)f2bf(f1[0]); a[5] = (short)f2bf(f1[1]);
  a[6] = (short)f2bf(f1[2]); a[7] = (short)f2bf(f1[3]);
  return a;
}

// Fused 2-layer MLP, register-blocked 2x (32 rows/wave). W fragments are read
// straight from global (prep_w layout) -> no W LDS, no __syncthreads.
// LDS = 16KB (per-wave h1 transpose buffer only) -> occupancy is VGPR-limited
// (~4 waves/SIMD vs previous 2). One pair per wave, perfectly balanced grid.
__global__ __launch_bounds__(256, 4) void mlp_fused(
    const float* __restrict__ x,
    const float* __restrict__ b1, const float* __restrict__ b2,
    unsigned short* __restrict__ h, const int* __restrict__ elabel,
    float* __restrict__ out, int nNodes, int npairs, int E) {
  __shared__ unsigned short sH[NWAVES][16 * D];  // 16 KB total
  const int tid = threadIdx.x;
  const int wave = tid >> 6, lane = tid & 63;
  const int quad = lane >> 4, l16 = lane & 15;

  // labels: vectorized int4 -> float4, overlapped with x loads
  {
    const int E4 = E & ~3;
    for (int li = (blockIdx.x * 256 + tid) * 4; li < E4; li += gridDim.x * 256 * 4) {
      int4 lv = *(const int4*)&elabel[li];
      float4 fv = make_float4((float)lv.x, (float)lv.y, (float)lv.z, (float)lv.w);
      *(float4*)&out[E + li] = fv;
    }
    if (blockIdx.x == 0 && tid < (E & 3)) out[E + E4 + tid] = (float)elabel[E4 + tid];
  }

  const int p = blockIdx.x * NWAVES + wave;
  if (p >= npairs) return;

  float bias1[8], bias2[8];
  #pragma unroll
  for (int n0 = 0; n0 < 8; ++n0) { bias1[n0] = b1[n0 * 16 + l16]; bias2[n0] = b2[n0 * 16 + l16]; }

  const short8* wq1 = (const short8*)g_wq;              // layer 1 frags
  const short8* wq2 = (const short8*)(g_wq + 16384);    // layer 2 frags
  unsigned short* mysH = sH[wave];

  const int mbase = p * 32;
  const int m0 = mbase + l16;
  const int m1 = m0 + 16;
  floatx4 xf0[8], xf1[8];
  {
    const floatx4* xp0 = (const floatx4*)(x + (size_t)m0 * D + quad * 8);
    const floatx4* xp1 = (const floatx4*)(x + (size_t)m1 * D + quad * 8);
    const bool v0 = (m0 < nNodes), v1 = (m1 < nNodes);
    #pragma unroll
    for (int i = 0; i < 8; ++i) {
      const int o = (i >> 1) * 8 + (i & 1);
      xf0[i] = v0 ? xp0[o] : (floatx4){0.f, 0.f, 0.f, 0.f};
      xf1[i] = v1 ? xp1[o] : (floatx4){0.f, 0.f, 0.f, 0.f};
    }
  }
  // ---- layer 1 ----
  floatx4 acc0[8], acc1[8];
  #pragma unroll
  for (int n0 = 0; n0 < 8; ++n0) {
    acc0[n0] = (floatx4){0.f, 0.f, 0.f, 0.f};
    acc1[n0] = (floatx4){0.f, 0.f, 0.f, 0.f};
  }
  #pragma unroll
  for (int kk = 0; kk < 4; ++kk) {
    const short8 a0 = cvt_a(xf0[2 * kk], xf0[2 * kk + 1]);
    const short8 a1 = cvt_a(xf1[2 * kk], xf1[2 * kk + 1]);
    #pragma unroll
    for (int n0 = 0; n0 < 8; ++n0) {
      short8 b = wq1[(kk * 8 + n0) * 64 + lane];
      acc0[n0] = __builtin_amdgcn_mfma_f32_16x16x32_bf16(a0, b, acc0[n0], 0, 0, 0);
      acc1[n0] = __builtin_amdgcn_mfma_f32_16x16x32_bf16(a1, b, acc1[n0], 0, 0, 0);
    }
  }
  // epilogue 1, half 0 -> sH, then read A-frags
  short8 af0[4], af1[4];
  #pragma unroll
  for (int n0 = 0; n0 < 8; ++n0) {
    #pragma unroll
    for (int r = 0; r < 4; ++r) {
      float v = acc0[n0][r] + bias1[n0];
      v = v > 0.f ? v : 0.f;
      const int row = quad * 4 + r;
      const int g = 2 * n0 + (l16 >> 3);
      mysH[row * D + (((g ^ row) & 15) << 3) + (l16 & 7)] = f2bf(v);
    }
  }
  #pragma unroll
  for (int kk = 0; kk < 4; ++kk)
    af0[kk] = *(const short8*)&mysH[l16 * D + ((((kk * 4 + quad) ^ l16) & 15) << 3)];
  // epilogue 1, half 1 -> sH (per-wave in-order overwrite is safe)
  #pragma unroll
  for (int n0 = 0; n0 < 8; ++n0) {
    #pragma unroll
    for (int r = 0; r < 4; ++r) {
      float v = acc1[n0][r] + bias1[n0];
      v = v > 0.f ? v : 0.f;
      const int row = quad * 4 + r;
      const int g = 2 * n0 + (l16 >> 3);
      mysH[row * D + (((g ^ row) & 15) << 3) + (l16 & 7)] = f2bf(v);
    }
  }
  #pragma unroll
  for (int kk = 0; kk < 4; ++kk)
    af1[kk] = *(const short8*)&mysH[l16 * D + ((((kk * 4 + quad) ^ l16) & 15) << 3)];
  // ---- layer 2 ----
  #pragma unroll
  for (int n0 = 0; n0 < 8; ++n0) {
    acc0[n0] = (floatx4){0.f, 0.f, 0.f, 0.f};
    acc1[n0] = (floatx4){0.f, 0.f, 0.f, 0.f};
  }
  #pragma unroll
  for (int kk = 0; kk < 4; ++kk) {
    #pragma unroll
    for (int n0 = 0; n0 < 8; ++n0) {
      short8 b = wq2[(kk * 8 + n0) * 64 + lane];
      acc0[n0] = __builtin_amdgcn_mfma_f32_16x16x32_bf16(af0[kk], b, acc0[n0], 0, 0, 0);
      acc1[n0] = __builtin_amdgcn_mfma_f32_16x16x32_bf16(af1[kk], b, acc1[n0], 0, 0, 0);
    }
  }
  // epilogue 2 + store, half 0
  #pragma unroll
  for (int n0 = 0; n0 < 8; ++n0) {
    #pragma unroll
    for (int r = 0; r < 4; ++r) {
      float v = acc0[n0][r] + bias2[n0];
      v = v > 0.f ? v : 0.f;
      const int row = quad * 4 + r;
      const int g = 2 * n0 + (l16 >> 3);
      mysH[row * D + (((g ^ row) & 15) << 3) + (l16 & 7)] = f2bf(v);
    }
  }
  #pragma unroll
  for (int i = 0; i < 4; ++i) {
    const int row = i * 4 + quad;
    short8 vrow = *(const short8*)&mysH[row * D + (((l16 ^ row) & 15) << 3)];
    const int g = mbase + row;
    if (g < nNodes) *(short8*)&h[(size_t)g * D + l16 * 8] = vrow;
  }
  // epilogue 2 + store, half 1
  #pragma unroll
  for (int n0 = 0; n0 < 8; ++n0) {
    #pragma unroll
    for (int r = 0; r < 4; ++r) {
      float v = acc1[n0][r] + bias2[n0];
      v = v > 0.f ? v : 0.f;
      const int row = quad * 4 + r;
      const int g = 2 * n0 + (l16 >> 3);
      mysH[row * D + (((g ^ row) & 15) << 3) + (l16 & 7)] = f2bf(v);
    }
  }
  #pragma unroll
  for (int i = 0; i < 4; ++i) {
    const int row = i * 4 + quad;
    short8 vrow = *(const short8*)&mysH[row * D + (((l16 ^ row) & 15) << 3)];
    const int g = mbase + 16 + row;
    if (g < nNodes) *(short8*)&h[(size_t)g * D + l16 * 8] = vrow;
  }
}

__device__ __forceinline__ float dot2bf(unsigned a, unsigned b, float acc) {
  float a0 = __uint_as_float(a << 16);
  float a1 = __uint_as_float(a & 0xFFFF0000u);
  float b0 = __uint_as_float(b << 16);
  float b1 = __uint_as_float(b & 0xFFFF0000u);
  acc = fmaf(a0, b0, acc);
  acc = fmaf(a1, b1, acc);
  return acc;
}

__device__ __forceinline__ float edge_dot(const uint4& a, const uint4& b) {
  float acc = 0.f;
  acc = dot2bf(a.x, b.x, acc);
  acc = dot2bf(a.y, b.y, acc);
  acc = dot2bf(a.z, b.z, acc);
  acc = dot2bf(a.w, b.w, acc);
  acc += __shfl_xor(acc, 8);
  acc += __shfl_xor(acc, 4);
  acc += __shfl_xor(acc, 2);
  acc += __shfl_xor(acc, 1);
  return acc;
}

// Edge decode: 16 lanes/edge, 8 edges per group -> 16 gathers (256B) in flight.
// One-shot blocks (3907): block churn keeps the load pipe full.
__global__ __launch_bounds__(256) void edge_kernel(
    const unsigned short* __restrict__ h2, const int* __restrict__ eidx,
    float* __restrict__ out, int E) {
  const int sub = threadIdx.x & 15;
  const int grp = (blockIdx.x * 256 + threadIdx.x) >> 4;
  const int e0 = grp * 8;
  if (e0 + 8 <= E) {
    const int4 s0 = *(const int4*)&eidx[e0];
    const int4 s1 = *(const int4*)&eidx[e0 + 4];
    const int4 t0 = *(const int4*)&eidx[E + e0];
    const int4 t1 = *(const int4*)&eidx[E + e0 + 4];
    int s[8] = {s0.x, s0.y, s0.z, s0.w, s1.x, s1.y, s1.z, s1.w};
    int d[8] = {t0.x, t0.y, t0.z, t0.w, t1.x, t1.y, t1.z, t1.w};
    uint4 va[8], vb[8];
    #pragma unroll
    for (int i = 0; i < 8; ++i) {
      va[i] = *(const uint4*)(h2 + (((size_t)(unsigned)s[i]) << 7) + sub * 8);
      vb[i] = *(const uint4*)(h2 + (((size_t)(unsigned)d[i]) << 7) + sub * 8);
    }
    #pragma unroll
    for (int i = 0; i < 8; ++i) {
      float acc = edge_dot(va[i], vb[i]);
      if (sub == 0) out[e0 + i] = acc;
    }
  } else if (e0 < E) {
    for (int e = e0; e < E; ++e) {
      const int s = eidx[e];
      const int d = eidx[E + e];
      const uint4 ua = *(const uint4*)(h2 + (((size_t)(unsigned)s) << 7) + sub * 8);
      const uint4 ub = *(const uint4*)(h2 + (((size_t)(unsigned)d) << 7) + sub * 8);
      float acc = edge_dot(ua, ub);
      if (sub == 0) out[e] = acc;
    }
  }
}

extern "C" void kernel_launch(void* const* d_in, const int* in_sizes, int n_in,
                              void* d_out, int out_size, void* d_ws, size_t ws_size,
                              hipStream_t stream) {
  const float* x  = (const float*)d_in[0];
  const int* eidx = (const int*)d_in[1];
  const int* elab = (const int*)d_in[2];
  const float* W1 = (const float*)d_in[3];
  const float* b1 = (const float*)d_in[4];
  const float* W2 = (const float*)d_in[5];
  const float* b2 = (const float*)d_in[6];
  float* out = (float*)d_out;

  const int nNodes = in_sizes[0] / D;   // 100000
  const int E = in_sizes[2];            // 500000
  const int npairs = (nNodes + 31) / 32;

  unsigned short* h = (unsigned short*)d_ws;  // nNodes*128 bf16 = 25.6 MB

  prep_w<<<128, 256, 0, stream>>>(W1, W2);   // 32768 threads: exact

  const int nblk = (npairs + NWAVES - 1) / NWAVES;  // 782: one 32-row pair per wave
  mlp_fused<<<nblk, 256, 0, stream>>>(x, b1, b2, h, elab, out, nNodes, npairs, E);

  const int edgeBlocks = (E + 127) / 128;   // 8 edges per 16-lane group
  edge_kernel<<<edgeBlocks, 256, 0, stream>>>(h, eidx, out, E);
}

// Round 4
// 160.624 us; speedup vs baseline: 1.0210x; 1.0210x over previous
//
#include <hip/hip_runtime.h>

typedef __attribute__((ext_vector_type(8))) short short8;
typedef __attribute__((ext_vector_type(4))) float floatx4;

#define D 128
#define NWAVES 4

// bf16 MFMA B-fragment buffer for W1,W2: 2*128*128 bf16 = 64 KB.
// Module-scope device global (NOT workspace: ws_size is exactly nNodes*D*2).
__device__ unsigned short g_wq[2 * D * D];

__device__ __forceinline__ unsigned short f2bf(float f) {
  unsigned u = __float_as_uint(f);
  u += 0x7FFFu + ((u >> 16) & 1u);   // RNE
  return (unsigned short)(u >> 16);
}

// One-shot W prep: convert fp32 W1,W2 -> bf16 laid out in exact MFMA
// B-fragment order. Per layer: 32 fragments (kk*8+n0) x 64 lanes x 8 elems
// = 16384 elements. Total 32768 threads (128 blocks x 256).
//   g_wq[layer*16384 + fragid*512 + lane*8 + e]
//     = W[(kk*32 + (lane>>4)*8 + e)*D + n0*16 + (lane&15)]
__global__ __launch_bounds__(256) void prep_w(const float* __restrict__ W1,
                                              const float* __restrict__ W2) {
  const int t = blockIdx.x * 256 + threadIdx.x;   // 32768 total
  const int layer = t >> 14;
  const int r = t & 16383;
  const int fragid = r >> 9;          // kk*8 + n0, [0,32)
  const int lane = (r >> 3) & 63;
  const int e = r & 7;
  const int kk = fragid >> 3, n0 = fragid & 7;
  const int k = kk * 32 + (lane >> 4) * 8 + e;    // [0,128)
  const int n = n0 * 16 + (lane & 15);            // [0,128)
  const float* W = layer ? W2 : W1;
  g_wq[t] = f2bf(W[k * D + n]);
}

__device__ __forceinline__ short8 cvt_a(const floatx4& f0, const floatx4& f1) {
  short8 a;
  a[0] = (short)f2bf(f0[0]); a[1] = (short)f2bf(f0[1]);
  a[2] = (short)f2bf(f0[2]); a[3] = (short)f2bf(f0[3]);
  a[4] = (short)f2bf(f1[0]); a[5] = (short)f2bf(f1[1]);
  a[6] = (short)f2bf(f1[2]); a[7] = (short)f2bf(f1[3]);
  return a;
}

// Fused 2-layer MLP, register-blocked 2x (32 rows/wave). W fragments read
// straight from global (prep_w layout) -> no W LDS, no __syncthreads.
// __launch_bounds__(256,3): cap ~170 VGPR -> NO SPILL (round-3's (256,4)
// capped at 128 unified and spilled ~57 MB to scratch). 3 waves/SIMD matches
// the grid's 12.2 waves/CU, so nothing is lost vs 4/SIMD.
__global__ __launch_bounds__(256, 3) void mlp_fused(
    const float* __restrict__ x,
    const float* __restrict__ b1, const float* __restrict__ b2,
    unsigned short* __restrict__ h, const int* __restrict__ elabel,
    float* __restrict__ out, int nNodes, int npairs, int E) {
  __shared__ unsigned short sH[NWAVES][16 * D];  // 16 KB total
  const int tid = threadIdx.x;
  const int wave = tid >> 6, lane = tid & 63;
  const int quad = lane >> 4, l16 = lane & 15;

  // labels: vectorized int4 -> float4
  {
    const int E4 = E & ~3;
    for (int li = (blockIdx.x * 256 + tid) * 4; li < E4; li += gridDim.x * 256 * 4) {
      int4 lv = *(const int4*)&elabel[li];
      float4 fv = make_float4((float)lv.x, (float)lv.y, (float)lv.z, (float)lv.w);
      *(float4*)&out[E + li] = fv;
    }
    if (blockIdx.x == 0 && tid < (E & 3)) out[E + E4 + tid] = (float)elabel[E4 + tid];
  }

  const int p = blockIdx.x * NWAVES + wave;
  if (p >= npairs) return;

  float bias1[8], bias2[8];
  #pragma unroll
  for (int n0 = 0; n0 < 8; ++n0) { bias1[n0] = b1[n0 * 16 + l16]; bias2[n0] = b2[n0 * 16 + l16]; }

  const short8* wq1 = (const short8*)g_wq;              // layer 1 frags
  const short8* wq2 = (const short8*)(g_wq + 16384);    // layer 2 frags
  unsigned short* mysH = sH[wave];

  const int mbase = p * 32;
  const int m0 = mbase + l16;
  const int m1 = m0 + 16;
  // Load x (16x 16B, full MLP) then convert to bf16 A-frags IMMEDIATELY so
  // the 64 fp32 load registers die before the accumulators go live.
  short8 a0[4], a1[4];
  {
    const floatx4* xp0 = (const floatx4*)(x + (size_t)m0 * D + quad * 8);
    const floatx4* xp1 = (const floatx4*)(x + (size_t)m1 * D + quad * 8);
    const bool v0 = (m0 < nNodes), v1 = (m1 < nNodes);
    floatx4 xf0[8], xf1[8];
    #pragma unroll
    for (int i = 0; i < 8; ++i) {
      const int o = (i >> 1) * 8 + (i & 1);
      xf0[i] = v0 ? xp0[o] : (floatx4){0.f, 0.f, 0.f, 0.f};
      xf1[i] = v1 ? xp1[o] : (floatx4){0.f, 0.f, 0.f, 0.f};
    }
    #pragma unroll
    for (int kk = 0; kk < 4; ++kk) {
      a0[kk] = cvt_a(xf0[2 * kk], xf0[2 * kk + 1]);
      a1[kk] = cvt_a(xf1[2 * kk], xf1[2 * kk + 1]);
    }
  }
  // ---- layer 1 ----
  floatx4 acc0[8], acc1[8];
  #pragma unroll
  for (int n0 = 0; n0 < 8; ++n0) {
    acc0[n0] = (floatx4){0.f, 0.f, 0.f, 0.f};
    acc1[n0] = (floatx4){0.f, 0.f, 0.f, 0.f};
  }
  #pragma unroll
  for (int kk = 0; kk < 4; ++kk) {
    #pragma unroll
    for (int n0 = 0; n0 < 8; ++n0) {
      short8 b = wq1[(kk * 8 + n0) * 64 + lane];
      acc0[n0] = __builtin_amdgcn_mfma_f32_16x16x32_bf16(a0[kk], b, acc0[n0], 0, 0, 0);
      acc1[n0] = __builtin_amdgcn_mfma_f32_16x16x32_bf16(a1[kk], b, acc1[n0], 0, 0, 0);
    }
  }
  // epilogue 1, half 0 -> sH, then read A-frags
  short8 af0[4], af1[4];
  #pragma unroll
  for (int n0 = 0; n0 < 8; ++n0) {
    #pragma unroll
    for (int r = 0; r < 4; ++r) {
      float v = acc0[n0][r] + bias1[n0];
      v = v > 0.f ? v : 0.f;
      const int row = quad * 4 + r;
      const int g = 2 * n0 + (l16 >> 3);
      mysH[row * D + (((g ^ row) & 15) << 3) + (l16 & 7)] = f2bf(v);
    }
  }
  #pragma unroll
  for (int kk = 0; kk < 4; ++kk)
    af0[kk] = *(const short8*)&mysH[l16 * D + ((((kk * 4 + quad) ^ l16) & 15) << 3)];
  // epilogue 1, half 1 -> sH (per-wave in-order overwrite is safe)
  #pragma unroll
  for (int n0 = 0; n0 < 8; ++n0) {
    #pragma unroll
    for (int r = 0; r < 4; ++r) {
      float v = acc1[n0][r] + bias1[n0];
      v = v > 0.f ? v : 0.f;
      const int row = quad * 4 + r;
      const int g = 2 * n0 + (l16 >> 3);
      mysH[row * D + (((g ^ row) & 15) << 3) + (l16 & 7)] = f2bf(v);
    }
  }
  #pragma unroll
  for (int kk = 0; kk < 4; ++kk)
    af1[kk] = *(const short8*)&mysH[l16 * D + ((((kk * 4 + quad) ^ l16) & 15) << 3)];
  // ---- layer 2 ----
  #pragma unroll
  for (int n0 = 0; n0 < 8; ++n0) {
    acc0[n0] = (floatx4){0.f, 0.f, 0.f, 0.f};
    acc1[n0] = (floatx4){0.f, 0.f, 0.f, 0.f};
  }
  #pragma unroll
  for (int kk = 0; kk < 4; ++kk) {
    #pragma unroll
    for (int n0 = 0; n0 < 8; ++n0) {
      short8 b = wq2[(kk * 8 + n0) * 64 + lane];
      acc0[n0] = __builtin_amdgcn_mfma_f32_16x16x32_bf16(af0[kk], b, acc0[n0], 0, 0, 0);
      acc1[n0] = __builtin_amdgcn_mfma_f32_16x16x32_bf16(af1[kk], b, acc1[n0], 0, 0, 0);
    }
  }
  // epilogue 2 + store, half 0
  #pragma unroll
  for (int n0 = 0; n0 < 8; ++n0) {
    #pragma unroll
    for (int r = 0; r < 4; ++r) {
      float v = acc0[n0][r] + bias2[n0];
      v = v > 0.f ? v : 0.f;
      const int row = quad * 4 + r;
      const int g = 2 * n0 + (l16 >> 3);
      mysH[row * D + (((g ^ row) & 15) << 3) + (l16 & 7)] = f2bf(v);
    }
  }
  #pragma unroll
  for (int i = 0; i < 4; ++i) {
    const int row = i * 4 + quad;
    short8 vrow = *(const short8*)&mysH[row * D + (((l16 ^ row) & 15) << 3)];
    const int g = mbase + row;
    if (g < nNodes) *(short8*)&h[(size_t)g * D + l16 * 8] = vrow;
  }
  // epilogue 2 + store, half 1
  #pragma unroll
  for (int n0 = 0; n0 < 8; ++n0) {
    #pragma unroll
    for (int r = 0; r < 4; ++r) {
      float v = acc1[n0][r] + bias2[n0];
      v = v > 0.f ? v : 0.f;
      const int row = quad * 4 + r;
      const int g = 2 * n0 + (l16 >> 3);
      mysH[row * D + (((g ^ row) & 15) << 3) + (l16 & 7)] = f2bf(v);
    }
  }
  #pragma unroll
  for (int i = 0; i < 4; ++i) {
    const int row = i * 4 + quad;
    short8 vrow = *(const short8*)&mysH[row * D + (((l16 ^ row) & 15) << 3)];
    const int g = mbase + 16 + row;
    if (g < nNodes) *(short8*)&h[(size_t)g * D + l16 * 8] = vrow;
  }
}

__device__ __forceinline__ float dot2bf(unsigned a, unsigned b, float acc) {
  float a0 = __uint_as_float(a << 16);
  float a1 = __uint_as_float(a & 0xFFFF0000u);
  float b0 = __uint_as_float(b << 16);
  float b1 = __uint_as_float(b & 0xFFFF0000u);
  acc = fmaf(a0, b0, acc);
  acc = fmaf(a1, b1, acc);
  return acc;
}

__device__ __forceinline__ float edge_dot(const uint4& a, const uint4& b) {
  float acc = 0.f;
  acc = dot2bf(a.x, b.x, acc);
  acc = dot2bf(a.y, b.y, acc);
  acc = dot2bf(a.z, b.z, acc);
  acc = dot2bf(a.w, b.w, acc);
  acc += __shfl_xor(acc, 8);
  acc += __shfl_xor(acc, 4);
  acc += __shfl_xor(acc, 2);
  acc += __shfl_xor(acc, 1);
  return acc;
}

// Edge decode: 16 lanes/edge, 8 edges per group -> 16 gathers (256B) in flight.
__global__ __launch_bounds__(256) void edge_kernel(
    const unsigned short* __restrict__ h2, const int* __restrict__ eidx,
    float* __restrict__ out, int E) {
  const int sub = threadIdx.x & 15;
  const int grp = (blockIdx.x * 256 + threadIdx.x) >> 4;
  const int e0 = grp * 8;
  if (e0 + 8 <= E) {
    const int4 s0 = *(const int4*)&eidx[e0];
    const int4 s1 = *(const int4*)&eidx[e0 + 4];
    const int4 t0 = *(const int4*)&eidx[E + e0];
    const int4 t1 = *(const int4*)&eidx[E + e0 + 4];
    int s[8] = {s0.x, s0.y, s0.z, s0.w, s1.x, s1.y, s1.z, s1.w};
    int d[8] = {t0.x, t0.y, t0.z, t0.w, t1.x, t1.y, t1.z, t1.w};
    uint4 va[8], vb[8];
    #pragma unroll
    for (int i = 0; i < 8; ++i) {
      va[i] = *(const uint4*)(h2 + (((size_t)(unsigned)s[i]) << 7) + sub * 8);
      vb[i] = *(const uint4*)(h2 + (((size_t)(unsigned)d[i]) << 7) + sub * 8);
    }
    #pragma unroll
    for (int i = 0; i < 8; ++i) {
      float acc = edge_dot(va[i], vb[i]);
      if (sub == 0) out[e0 + i] = acc;
    }
  } else if (e0 < E) {
    for (int e = e0; e < E; ++e) {
      const int s = eidx[e];
      const int d = eidx[E + e];
      const uint4 ua = *(const uint4*)(h2 + (((size_t)(unsigned)s) << 7) + sub * 8);
      const uint4 ub = *(const uint4*)(h2 + (((size_t)(unsigned)d) << 7) + sub * 8);
      float acc = edge_dot(ua, ub);
      if (sub == 0) out[e] = acc;
    }
  }
}

extern "C" void kernel_launch(void* const* d_in, const int* in_sizes, int n_in,
                              void* d_out, int out_size, void* d_ws, size_t ws_size,
                              hipStream_t stream) {
  const float* x  = (const float*)d_in[0];
  const int* eidx = (const int*)d_in[1];
  const int* elab = (const int*)d_in[2];
  const float* W1 = (const float*)d_in[3];
  const float* b1 = (const float*)d_in[4];
  const float* W2 = (const float*)d_in[5];
  const float* b2 = (const float*)d_in[6];
  float* out = (float*)d_out;

  const int nNodes = in_sizes[0] / D;   // 100000
  const int E = in_sizes[2];            // 500000
  const int npairs = (nNodes + 31) / 32;

  unsigned short* h = (unsigned short*)d_ws;  // nNodes*128 bf16 = 25.6 MB

  prep_w<<<128, 256, 0, stream>>>(W1, W2);   // 32768 threads: exact

  const int nblk = (npairs + NWAVES - 1) / NWAVES;  // 782: one 32-row pair per wave
  mlp_fused<<<nblk, 256, 0, stream>>>(x, b1, b2, h, elab, out, nNodes, npairs, E);

  const int edgeBlocks = (E + 127) / 128;   // 8 edges per 16-lane group
  edge_kernel<<<edgeBlocks, 256, 0, stream>>>(h, eidx, out, E);
}

// Round 5
// 150.535 us; speedup vs baseline: 1.0894x; 1.0670x over previous
//
#include <hip/hip_runtime.h>

typedef __attribute__((ext_vector_type(8))) short short8;
typedef __attribute__((ext_vector_type(4))) float floatx4;

#define D 128
#define NWAVES 4

// bf16 MFMA B-fragment buffer for W1,W2: 2*128*128 bf16 = 64 KB.
// Module-scope device global (NOT workspace: ws_size is exactly nNodes*D*2).
__device__ unsigned short g_wq[2 * D * D];

__device__ __forceinline__ unsigned short f2bf(float f) {
  unsigned u = __float_as_uint(f);
  u += 0x7FFFu + ((u >> 16) & 1u);   // RNE
  return (unsigned short)(u >> 16);
}

// One-shot prep: blocks 0..127 convert fp32 W1,W2 -> bf16 MFMA B-fragment
// order (g_wq[layer*16384 + fragid*512 + lane*8 + e] =
// W[(kk*32+(lane>>4)*8+e)*D + n0*16+(lane&15)]); ALL blocks copy edge labels
// (int -> float) so the label pass is off mlp_fused's critical path.
__global__ __launch_bounds__(256) void prep_w(const float* __restrict__ W1,
                                              const float* __restrict__ W2,
                                              const int* __restrict__ elabel,
                                              float* __restrict__ out, int E) {
  const int t = blockIdx.x * 256 + threadIdx.x;   // 512 blocks = 131072 threads
  if (t < 32768) {
    const int layer = t >> 14;
    const int r = t & 16383;
    const int fragid = r >> 9;          // kk*8 + n0, [0,32)
    const int lane = (r >> 3) & 63;
    const int e = r & 7;
    const int kk = fragid >> 3, n0 = fragid & 7;
    const int k = kk * 32 + (lane >> 4) * 8 + e;    // [0,128)
    const int n = n0 * 16 + (lane & 15);            // [0,128)
    const float* W = layer ? W2 : W1;
    g_wq[t] = f2bf(W[k * D + n]);
  }
  const int E4 = E & ~3;
  for (int li = t * 4; li < E4; li += gridDim.x * 256 * 4) {
    int4 lv = *(const int4*)&elabel[li];
    float4 fv = make_float4((float)lv.x, (float)lv.y, (float)lv.z, (float)lv.w);
    *(float4*)&out[E + li] = fv;
  }
  if (t < (E & 3)) out[E + E4 + t] = (float)elabel[E4 + t];
}

__device__ __forceinline__ short8 cvt_a(const floatx4& f0, const floatx4& f1) {
  short8 a;
  a[0] = (short)f2bf(f0[0]); a[1] = (short)f2bf(f0[1]);
  a[2] = (short)f2bf(f0[2]); a[3] = (short)f2bf(f0[3]);
  a[4] = (short)f2bf(f1[0]); a[5] = (short)f2bf(f1[1]);
  a[6] = (short)f2bf(f1[2]); a[7] = (short)f2bf(f1[3]);
  return a;
}

// Fused 2-layer MLP, register-blocked 2x (32 rows/wave).
// LATENCY FIX (r4 post-mortem): all 32 B-fragments of a layer are prefetched
// into registers (128 VGPR) before the MFMA block -> ONE ~300cy latency
// exposure per layer instead of 32 serialized load->MFMA round trips.
// Layer-2 fragments are issued before epilogue-1 so their latency hides under
// the LDS transpose. launch_bounds(256,2): cap 256 VGPR (peak ~235, no spill);
// the 782-block grid can only use ~2 waves/SIMD anyway.
__global__ __launch_bounds__(256, 2) void mlp_fused(
    const float* __restrict__ x,
    const float* __restrict__ b1, const float* __restrict__ b2,
    unsigned short* __restrict__ h, int nNodes, int npairs) {
  __shared__ unsigned short sH[NWAVES][16 * D];  // 16 KB total
  const int tid = threadIdx.x;
  const int wave = tid >> 6, lane = tid & 63;
  const int quad = lane >> 4, l16 = lane & 15;

  const int p = blockIdx.x * NWAVES + wave;
  if (p >= npairs) return;

  const short8* wq1 = (const short8*)g_wq;              // layer 1 frags
  const short8* wq2 = (const short8*)(g_wq + 16384);    // layer 2 frags
  unsigned short* mysH = sH[wave];

  const int mbase = p * 32;
  const int m0 = mbase + l16;
  const int m1 = m0 + 16;
  // Load x (16x 16B) and convert to bf16 A-frags immediately (fp32 regs die).
  short8 a0[4], a1[4];
  {
    const floatx4* xp0 = (const floatx4*)(x + (size_t)m0 * D + quad * 8);
    const floatx4* xp1 = (const floatx4*)(x + (size_t)m1 * D + quad * 8);
    const bool v0 = (m0 < nNodes), v1 = (m1 < nNodes);
    floatx4 xf0[8], xf1[8];
    #pragma unroll
    for (int i = 0; i < 8; ++i) {
      const int o = (i >> 1) * 8 + (i & 1);
      xf0[i] = v0 ? xp0[o] : (floatx4){0.f, 0.f, 0.f, 0.f};
      xf1[i] = v1 ? xp1[o] : (floatx4){0.f, 0.f, 0.f, 0.f};
    }
    #pragma unroll
    for (int kk = 0; kk < 4; ++kk) {
      a0[kk] = cvt_a(xf0[2 * kk], xf0[2 * kk + 1]);
      a1[kk] = cvt_a(xf1[2 * kk], xf1[2 * kk + 1]);
    }
  }
  // ---- layer 1: prefetch ALL B-frags, then pure-MFMA block ----
  short8 bf[32];
  #pragma unroll
  for (int i = 0; i < 32; ++i) bf[i] = wq1[i * 64 + lane];
  __builtin_amdgcn_sched_barrier(0);
  floatx4 acc0[8], acc1[8];
  #pragma unroll
  for (int n0 = 0; n0 < 8; ++n0) {
    acc0[n0] = (floatx4){0.f, 0.f, 0.f, 0.f};
    acc1[n0] = (floatx4){0.f, 0.f, 0.f, 0.f};
  }
  #pragma unroll
  for (int kk = 0; kk < 4; ++kk) {
    #pragma unroll
    for (int n0 = 0; n0 < 8; ++n0) {
      acc0[n0] = __builtin_amdgcn_mfma_f32_16x16x32_bf16(a0[kk], bf[kk * 8 + n0], acc0[n0], 0, 0, 0);
      acc1[n0] = __builtin_amdgcn_mfma_f32_16x16x32_bf16(a1[kk], bf[kk * 8 + n0], acc1[n0], 0, 0, 0);
    }
  }
  __builtin_amdgcn_sched_barrier(0);
  // Prefetch layer-2 B-frags NOW: latency hides under epilogue-1 LDS work.
  #pragma unroll
  for (int i = 0; i < 32; ++i) bf[i] = wq2[i * 64 + lane];
  __builtin_amdgcn_sched_barrier(0);
  // bias1 (deferred load: keeps MFMA-phase register peak down)
  float bias1[8];
  #pragma unroll
  for (int n0 = 0; n0 < 8; ++n0) bias1[n0] = b1[n0 * 16 + l16];
  // epilogue 1, half 0 -> sH, then read A-frags
  short8 af0[4], af1[4];
  #pragma unroll
  for (int n0 = 0; n0 < 8; ++n0) {
    #pragma unroll
    for (int r = 0; r < 4; ++r) {
      float v = acc0[n0][r] + bias1[n0];
      v = v > 0.f ? v : 0.f;
      const int row = quad * 4 + r;
      const int g = 2 * n0 + (l16 >> 3);
      mysH[row * D + (((g ^ row) & 15) << 3) + (l16 & 7)] = f2bf(v);
    }
  }
  #pragma unroll
  for (int kk = 0; kk < 4; ++kk)
    af0[kk] = *(const short8*)&mysH[l16 * D + ((((kk * 4 + quad) ^ l16) & 15) << 3)];
  // epilogue 1, half 1 -> sH (per-wave in-order overwrite is safe)
  #pragma unroll
  for (int n0 = 0; n0 < 8; ++n0) {
    #pragma unroll
    for (int r = 0; r < 4; ++r) {
      float v = acc1[n0][r] + bias1[n0];
      v = v > 0.f ? v : 0.f;
      const int row = quad * 4 + r;
      const int g = 2 * n0 + (l16 >> 3);
      mysH[row * D + (((g ^ row) & 15) << 3) + (l16 & 7)] = f2bf(v);
    }
  }
  #pragma unroll
  for (int kk = 0; kk < 4; ++kk)
    af1[kk] = *(const short8*)&mysH[l16 * D + ((((kk * 4 + quad) ^ l16) & 15) << 3)];
  // ---- layer 2 ----
  #pragma unroll
  for (int n0 = 0; n0 < 8; ++n0) {
    acc0[n0] = (floatx4){0.f, 0.f, 0.f, 0.f};
    acc1[n0] = (floatx4){0.f, 0.f, 0.f, 0.f};
  }
  #pragma unroll
  for (int kk = 0; kk < 4; ++kk) {
    #pragma unroll
    for (int n0 = 0; n0 < 8; ++n0) {
      acc0[n0] = __builtin_amdgcn_mfma_f32_16x16x32_bf16(af0[kk], bf[kk * 8 + n0], acc0[n0], 0, 0, 0);
      acc1[n0] = __builtin_amdgcn_mfma_f32_16x16x32_bf16(af1[kk], bf[kk * 8 + n0], acc1[n0], 0, 0, 0);
    }
  }
  __builtin_amdgcn_sched_barrier(0);
  float bias2[8];
  #pragma unroll
  for (int n0 = 0; n0 < 8; ++n0) bias2[n0] = b2[n0 * 16 + l16];
  // epilogue 2 + store, half 0
  #pragma unroll
  for (int n0 = 0; n0 < 8; ++n0) {
    #pragma unroll
    for (int r = 0; r < 4; ++r) {
      float v = acc0[n0][r] + bias2[n0];
      v = v > 0.f ? v : 0.f;
      const int row = quad * 4 + r;
      const int g = 2 * n0 + (l16 >> 3);
      mysH[row * D + (((g ^ row) & 15) << 3) + (l16 & 7)] = f2bf(v);
    }
  }
  #pragma unroll
  for (int i = 0; i < 4; ++i) {
    const int row = i * 4 + quad;
    short8 vrow = *(const short8*)&mysH[row * D + (((l16 ^ row) & 15) << 3)];
    const int g = mbase + row;
    if (g < nNodes) *(short8*)&h[(size_t)g * D + l16 * 8] = vrow;
  }
  // epilogue 2 + store, half 1
  #pragma unroll
  for (int n0 = 0; n0 < 8; ++n0) {
    #pragma unroll
    for (int r = 0; r < 4; ++r) {
      float v = acc1[n0][r] + bias2[n0];
      v = v > 0.f ? v : 0.f;
      const int row = quad * 4 + r;
      const int g = 2 * n0 + (l16 >> 3);
      mysH[row * D + (((g ^ row) & 15) << 3) + (l16 & 7)] = f2bf(v);
    }
  }
  #pragma unroll
  for (int i = 0; i < 4; ++i) {
    const int row = i * 4 + quad;
    short8 vrow = *(const short8*)&mysH[row * D + (((l16 ^ row) & 15) << 3)];
    const int g = mbase + 16 + row;
    if (g < nNodes) *(short8*)&h[(size_t)g * D + l16 * 8] = vrow;
  }
}

__device__ __forceinline__ float dot2bf(unsigned a, unsigned b, float acc) {
  float a0 = __uint_as_float(a << 16);
  float a1 = __uint_as_float(a & 0xFFFF0000u);
  float b0 = __uint_as_float(b << 16);
  float b1 = __uint_as_float(b & 0xFFFF0000u);
  acc = fmaf(a0, b0, acc);
  acc = fmaf(a1, b1, acc);
  return acc;
}

__device__ __forceinline__ float edge_dot(const uint4& a, const uint4& b) {
  float acc = 0.f;
  acc = dot2bf(a.x, b.x, acc);
  acc = dot2bf(a.y, b.y, acc);
  acc = dot2bf(a.z, b.z, acc);
  acc = dot2bf(a.w, b.w, acc);
  acc += __shfl_xor(acc, 8);
  acc += __shfl_xor(acc, 4);
  acc += __shfl_xor(acc, 2);
  acc += __shfl_xor(acc, 1);
  return acc;
}

// Edge decode: 16 lanes/edge, 8 edges per group -> 16 gathers (256B) in flight.
__global__ __launch_bounds__(256) void edge_kernel(
    const unsigned short* __restrict__ h2, const int* __restrict__ eidx,
    float* __restrict__ out, int E) {
  const int sub = threadIdx.x & 15;
  const int grp = (blockIdx.x * 256 + threadIdx.x) >> 4;
  const int e0 = grp * 8;
  if (e0 + 8 <= E) {
    const int4 s0 = *(const int4*)&eidx[e0];
    const int4 s1 = *(const int4*)&eidx[e0 + 4];
    const int4 t0 = *(const int4*)&eidx[E + e0];
    const int4 t1 = *(const int4*)&eidx[E + e0 + 4];
    int s[8] = {s0.x, s0.y, s0.z, s0.w, s1.x, s1.y, s1.z, s1.w};
    int d[8] = {t0.x, t0.y, t0.z, t0.w, t1.x, t1.y, t1.z, t1.w};
    uint4 va[8], vb[8];
    #pragma unroll
    for (int i = 0; i < 8; ++i) {
      va[i] = *(const uint4*)(h2 + (((size_t)(unsigned)s[i]) << 7) + sub * 8);
      vb[i] = *(const uint4*)(h2 + (((size_t)(unsigned)d[i]) << 7) + sub * 8);
    }
    #pragma unroll
    for (int i = 0; i < 8; ++i) {
      float acc = edge_dot(va[i], vb[i]);
      if (sub == 0) out[e0 + i] = acc;
    }
  } else if (e0 < E) {
    for (int e = e0; e < E; ++e) {
      const int s = eidx[e];
      const int d = eidx[E + e];
      const uint4 ua = *(const uint4*)(h2 + (((size_t)(unsigned)s) << 7) + sub * 8);
      const uint4 ub = *(const uint4*)(h2 + (((size_t)(unsigned)d) << 7) + sub * 8);
      float acc = edge_dot(ua, ub);
      if (sub == 0) out[e] = acc;
    }
  }
}

extern "C" void kernel_launch(void* const* d_in, const int* in_sizes, int n_in,
                              void* d_out, int out_size, void* d_ws, size_t ws_size,
                              hipStream_t stream) {
  const float* x  = (const float*)d_in[0];
  const int* eidx = (const int*)d_in[1];
  const int* elab = (const int*)d_in[2];
  const float* W1 = (const float*)d_in[3];
  const float* b1 = (const float*)d_in[4];
  const float* W2 = (const float*)d_in[5];
  const float* b2 = (const float*)d_in[6];
  float* out = (float*)d_out;

  const int nNodes = in_sizes[0] / D;   // 100000
  const int E = in_sizes[2];            // 500000
  const int npairs = (nNodes + 31) / 32;

  unsigned short* h = (unsigned short*)d_ws;  // nNodes*128 bf16 = 25.6 MB

  prep_w<<<512, 256, 0, stream>>>(W1, W2, elab, out, E);

  const int nblk = (npairs + NWAVES - 1) / NWAVES;  // 782: one 32-row pair per wave
  mlp_fused<<<nblk, 256, 0, stream>>>(x, b1, b2, h, nNodes, npairs);

  const int edgeBlocks = (E + 127) / 128;   // 8 edges per 16-lane group
  edge_kernel<<<edgeBlocks, 256, 0, stream>>>(h, eidx, out, E);
}